// Round 1
// baseline (1155.932 us; speedup 1.0000x reference)
//
#include <hip/hip_runtime.h>
#include <math.h>

#define BATCH 256
#define T 1024
#define IN 19
#define H 128

// tanh via v_exp_f32: tanh(x)=sign(x)*(1-2/(exp(2|x|)+1)); exact to ~1e-7.
__device__ __forceinline__ float fast_tanh(float x) {
    float ax = fabsf(x);
    float e  = __expf(2.0f * ax);
    float r  = 1.0f - 2.0f / (e + 1.0f);
    return copysignf(r, x);
}

// ---------------------------------------------------------------------------
// Single fused kernel. 256 blocks x 512 threads (8 waves, 2/SIMD, 1 block/CU).
// Pipeline (identical barrier/interval schedule to previous version):
//   S0 (tid   0..127, 2 waves): h0_k = tanh(Wih0.x_k + b0 + Whh0.h0_{k-1})
//   P  (tid 128..383, 4 waves): B_{k-1} = Wih1.h0_{k-1} + b1
//   S1 (tid 384..511, 2 waves): h1_{k-2} = tanh(B_{k-2} + Whh1.h1_{k-3})
// NEW layout: S0/S1 thread owns ONE unit x full 128-element row (128 weight
// VGPRs, 4 accumulators) -> no cross-lane reduction at all on the serial
// chain. h vectors read as uniform-address ds_read_b128 (pure broadcast,
// conflict-free). P: 2 threads/unit, 64-elem halves, single shfl_xor(1).
// pre0 kernel fused away: S0 stages x in 8-step LDS chunks (double-buffered,
// loaded 2 chunks ahead) and does the 19-FMA input projection inline.
// Unroll = 8 (not 16): total hot code ~27KB fits 32KB L1I; ring indices
// (k&3 etc.) stay compile-time static since ko strides 8.
// SIMD pairing (contiguous waves): {S0,P},{S0,P},{P,S1},{P,S1} - balanced.
// All groups execute exactly 1027 barriers.
// ---------------------------------------------------------------------------
__global__ __launch_bounds__(512, 2)
void fused_rnn(const float* __restrict__ x,      // [B,T,IN]
               const float* __restrict__ Wih0,   // [H,IN]
               const float* __restrict__ Whh0,   // [H,H]
               const float* __restrict__ bih0,
               const float* __restrict__ bhh0,
               const float* __restrict__ Wih1,   // [H,H]
               const float* __restrict__ Whh1,   // [H,H]
               const float* __restrict__ bih1,
               const float* __restrict__ bhh1,
               float* __restrict__ out) {        // [B,T,H]
    const int b   = blockIdx.x;
    const int tid = threadIdx.x;

    __shared__ __align__(16) float h0ring[4][H];
    __shared__ __align__(16) float h1ring[4][H];
    __shared__ __align__(16) float Bring[4][H];
    // x chunks: 8 steps x 19 floats, padded to stride 20 (pad slot zeroed
    // once; wI[19]=0 so the pad lane contributes 0 to the projection).
    __shared__ __align__(16) float xbuf[2][8 * 20];

    if (tid < 128) {
        // =================== S0 ===================
        const int u = tid;
        float wA[128];
        {
            const float* wr = Whh0 + (size_t)u * H;
#pragma unroll
            for (int c = 0; c < 128; c += 4) {
                float4 v = *(const float4*)&wr[c];
                wA[c] = v.x; wA[c+1] = v.y; wA[c+2] = v.z; wA[c+3] = v.w;
            }
        }
        float wI[20];
#pragma unroll
        for (int f = 0; f < IN; ++f) wI[f] = Wih0[u * IN + f];
        wI[19] = 0.0f;
        const float bias0 = bih0[u] + bhh0[u];

        // x staging: chunk = 8*IN = 152 elements; thread loads idx0=tid and
        // (tid<24) idx1=tid+128 of each chunk. Scatter into stride-20 slots.
        const float* xsrc = x + (size_t)b * T * IN;
        const int idx0  = tid;
        const int idx1  = tid + 128;
        const bool v1   = (idx1 < 8 * IN);
        const int slot0 = (idx0 / IN) * 20 + idx0 % IN;
        const int slot1 = (idx1 / IN) * 20 + idx1 % IN;

        if (tid < 8) { xbuf[0][tid * 20 + 19] = 0.0f; xbuf[1][tid * 20 + 19] = 0.0f; }
        // chunk 0 -> LDS
        xbuf[0][slot0] = xsrc[idx0];
        if (v1) xbuf[0][slot1] = xsrc[idx1];
        // chunk 1 -> regs (written to LDS at end of chunk 0)
        float xr0 = xsrc[8 * IN + idx0];
        float xr1 = v1 ? xsrc[8 * IN + idx1] : 0.0f;

        h0ring[3][u] = 0.0f;   // h0_{-1}
        __syncthreads();        // init barrier

        for (int ko = 0; ko < T; ko += 8) {
            const int cb = (ko >> 3) & 1;
            const float* xch = xbuf[cb];
#pragma unroll
            for (int j = 0; j < 8; ++j) {
                const int k = ko + j;
                const float* hp = h0ring[(k + 3) & 3];
                // ---- input projection (x broadcast from LDS) ----
                const float* xp = &xch[j * 20];
                float4 xv0 = *(const float4*)&xp[0];
                float4 xv1 = *(const float4*)&xp[4];
                float4 xv2 = *(const float4*)&xp[8];
                float4 xv3 = *(const float4*)&xp[12];
                float4 xv4 = *(const float4*)&xp[16];   // .w = pad (0 weight)
                float p0 = bias0, p1 = 0.0f;
                p0 = fmaf(xv0.x, wI[0],  p0); p1 = fmaf(xv0.y, wI[1],  p1);
                p0 = fmaf(xv0.z, wI[2],  p0); p1 = fmaf(xv0.w, wI[3],  p1);
                p0 = fmaf(xv1.x, wI[4],  p0); p1 = fmaf(xv1.y, wI[5],  p1);
                p0 = fmaf(xv1.z, wI[6],  p0); p1 = fmaf(xv1.w, wI[7],  p1);
                p0 = fmaf(xv2.x, wI[8],  p0); p1 = fmaf(xv2.y, wI[9],  p1);
                p0 = fmaf(xv2.z, wI[10], p0); p1 = fmaf(xv2.w, wI[11], p1);
                p0 = fmaf(xv3.x, wI[12], p0); p1 = fmaf(xv3.y, wI[13], p1);
                p0 = fmaf(xv3.z, wI[14], p0); p1 = fmaf(xv3.w, wI[15], p1);
                p0 = fmaf(xv4.x, wI[16], p0); p1 = fmaf(xv4.y, wI[17], p1);
                p0 = fmaf(xv4.z, wI[18], p0); p1 = fmaf(xv4.w, wI[19], p1);
                // ---- recurrence: full 128-row dot, broadcast h reads ----
                float a0 = 0.f, a1 = 0.f, a2 = 0.f, a3 = 0.f;
#pragma unroll
                for (int c = 0; c < 128; c += 16) {
                    float4 h0v = *(const float4*)&hp[c];
                    float4 h1v = *(const float4*)&hp[c + 4];
                    float4 h2v = *(const float4*)&hp[c + 8];
                    float4 h3v = *(const float4*)&hp[c + 12];
                    a0 = fmaf(wA[c+0],  h0v.x, a0); a0 = fmaf(wA[c+1],  h0v.y, a0);
                    a0 = fmaf(wA[c+2],  h0v.z, a0); a0 = fmaf(wA[c+3],  h0v.w, a0);
                    a1 = fmaf(wA[c+4],  h1v.x, a1); a1 = fmaf(wA[c+5],  h1v.y, a1);
                    a1 = fmaf(wA[c+6],  h1v.z, a1); a1 = fmaf(wA[c+7],  h1v.w, a1);
                    a2 = fmaf(wA[c+8],  h2v.x, a2); a2 = fmaf(wA[c+9],  h2v.y, a2);
                    a2 = fmaf(wA[c+10], h2v.z, a2); a2 = fmaf(wA[c+11], h2v.w, a2);
                    a3 = fmaf(wA[c+12], h3v.x, a3); a3 = fmaf(wA[c+13], h3v.y, a3);
                    a3 = fmaf(wA[c+14], h3v.z, a3); a3 = fmaf(wA[c+15], h3v.w, a3);
                }
                float s = ((a0 + a1) + (a2 + a3)) + (p0 + p1);
                h0ring[k & 3][u] = fast_tanh(s);
                if (j == 7) {
                    if (ko + 8 < T) {       // publish next chunk (pre-barrier)
                        float* xd = xbuf[cb ^ 1];
                        xd[slot0] = xr0;
                        if (v1) xd[slot1] = xr1;
                    }
                    if (ko + 16 < T) {      // fetch chunk+2 (15 intervals of cover)
                        const float* xs2 = xsrc + (size_t)(ko + 16) * IN;
                        xr0 = xs2[idx0];
                        if (v1) xr1 = xs2[idx1];
                    }
                }
                __syncthreads();
            }
        }
        __syncthreads();   // interval 1024
        __syncthreads();   // interval 1025
    } else if (tid < 384) {
        // =================== P ===================
        const int p    = tid - 128;
        const int u    = p >> 1;       // pair lanes (2u, 2u+1) share a unit
        const int half = p & 1;        // half of the 128-elem row
        float wP[64];
        {
            const float* wr = Wih1 + (size_t)u * H + half * 64;
#pragma unroll
            for (int c = 0; c < 64; c += 4) {
                float4 v = *(const float4*)&wr[c];
                wP[c] = v.x; wP[c+1] = v.y; wP[c+2] = v.z; wP[c+3] = v.w;
            }
        }
        const float biasP = bih1[u] + bhh1[u];

        __syncthreads();   // init barrier
        __syncthreads();   // interval 0 (no work)

        for (int ko = 1; ko < 1025; ko += 8) {
#pragma unroll
            for (int j = 0; j < 8; ++j) {
                const int k = ko + j;
                const float* hp = &h0ring[(k + 3) & 3][half * 64];
                float a0 = 0.f, a1 = 0.f;
#pragma unroll
                for (int c = 0; c < 64; c += 8) {
                    float4 hv0 = *(const float4*)&hp[c];
                    float4 hv1 = *(const float4*)&hp[c + 4];
                    a0 = fmaf(wP[c+0], hv0.x, a0); a0 = fmaf(wP[c+1], hv0.y, a0);
                    a0 = fmaf(wP[c+2], hv0.z, a0); a0 = fmaf(wP[c+3], hv0.w, a0);
                    a1 = fmaf(wP[c+4], hv1.x, a1); a1 = fmaf(wP[c+5], hv1.y, a1);
                    a1 = fmaf(wP[c+6], hv1.z, a1); a1 = fmaf(wP[c+7], hv1.w, a1);
                }
                float g = a0 + a1;
                g += __shfl_xor(g, 1);         // combine halves (quad-perm)
                if (!half) Bring[(k + 3) & 3][u] = g + biasP;
                __syncthreads();
            }
        }
        __syncthreads();   // interval 1025
    } else {
        // =================== S1 ===================
        const int u = tid - 384;
        float wA[128];
        {
            const float* wr = Whh1 + (size_t)u * H;
#pragma unroll
            for (int c = 0; c < 128; c += 4) {
                float4 v = *(const float4*)&wr[c];
                wA[c] = v.x; wA[c+1] = v.y; wA[c+2] = v.z; wA[c+3] = v.w;
            }
        }
        float* orow = out + (size_t)b * T * H + u;
        float sbuf[8];

        h1ring[3][u] = 0.0f;   // h1_{-1}
        __syncthreads();   // init barrier
        __syncthreads();   // interval 0
        __syncthreads();   // interval 1

        for (int ko = 2; ko < 1026; ko += 8) {
#pragma unroll
            for (int j = 0; j < 8; ++j) {
                const int k = ko + j;                 // t = k-2
                const float* hp = h1ring[(k + 1) & 3];
                float Bg = Bring[(k + 2) & 3][u];
                float a0 = 0.f, a1 = 0.f, a2 = 0.f, a3 = 0.f;
#pragma unroll
                for (int c = 0; c < 128; c += 16) {
                    float4 h0v = *(const float4*)&hp[c];
                    float4 h1v = *(const float4*)&hp[c + 4];
                    float4 h2v = *(const float4*)&hp[c + 8];
                    float4 h3v = *(const float4*)&hp[c + 12];
                    a0 = fmaf(wA[c+0],  h0v.x, a0); a0 = fmaf(wA[c+1],  h0v.y, a0);
                    a0 = fmaf(wA[c+2],  h0v.z, a0); a0 = fmaf(wA[c+3],  h0v.w, a0);
                    a1 = fmaf(wA[c+4],  h1v.x, a1); a1 = fmaf(wA[c+5],  h1v.y, a1);
                    a1 = fmaf(wA[c+6],  h1v.z, a1); a1 = fmaf(wA[c+7],  h1v.w, a1);
                    a2 = fmaf(wA[c+8],  h2v.x, a2); a2 = fmaf(wA[c+9],  h2v.y, a2);
                    a2 = fmaf(wA[c+10], h2v.z, a2); a2 = fmaf(wA[c+11], h2v.w, a2);
                    a3 = fmaf(wA[c+12], h3v.x, a3); a3 = fmaf(wA[c+13], h3v.y, a3);
                    a3 = fmaf(wA[c+14], h3v.z, a3); a3 = fmaf(wA[c+15], h3v.w, a3);
                }
                float h1v = fast_tanh(((a0 + a1) + (a2 + a3)) + Bg);
                h1ring[(k + 2) & 3][u] = h1v;
                sbuf[j] = h1v;
                if (j == 7) {                  // t = ko-2+j ends an 8-burst
                    const int t0 = ko - 2;     // first t of this burst
#pragma unroll
                    for (int i = 0; i < 8; ++i)
                        orow[(size_t)(t0 + i) * H] = sbuf[i];
                }
                __syncthreads();
            }
        }
        // no trailing barriers needed for S1 (last interval is 1025)
    }
}

// ---------------------------------------------------------------------------
extern "C" void kernel_launch(void* const* d_in, const int* in_sizes, int n_in,
                              void* d_out, int out_size, void* d_ws, size_t ws_size,
                              hipStream_t stream) {
    const float* x     = (const float*)d_in[0];
    const float* W_ih0 = (const float*)d_in[1];
    const float* W_hh0 = (const float*)d_in[2];
    const float* b_ih0 = (const float*)d_in[3];
    const float* b_hh0 = (const float*)d_in[4];
    const float* W_ih1 = (const float*)d_in[5];
    const float* W_hh1 = (const float*)d_in[6];
    const float* b_ih1 = (const float*)d_in[7];
    const float* b_hh1 = (const float*)d_in[8];

    float* out = (float*)d_out;

    fused_rnn<<<BATCH, 512, 0, stream>>>(x, W_ih0, W_hh0, b_ih0, b_hh0,
                                         W_ih1, W_hh1, b_ih1, b_hh1, out);
}

// Round 2
// 658.718 us; speedup vs baseline: 1.7548x; 1.7548x over previous
//
#include <hip/hip_runtime.h>
#include <math.h>

#define BATCH 256
#define T 1024
#define IN 19
#define H 128

// tanh via v_exp_f32: tanh(x)=sign(x)*(1-2/(exp(2|x|)+1)); exact to ~1e-7.
__device__ __forceinline__ float fast_tanh(float x) {
    float ax = fabsf(x);
    float e  = __expf(2.0f * ax);
    float r  = 1.0f - 2.0f / (e + 1.0f);
    return copysignf(r, x);
}

// DPP cross-lane move (VALU-only, no LDS pipe — replaces ds_bpermute shuffles).
template <int CTRL>
__device__ __forceinline__ float dppf(float v) {
    return __int_as_float(__builtin_amdgcn_update_dpp(
        0, __float_as_int(v), CTRL, 0xF, 0xF, true));
}
#define XOR1 0xB1   // quad_perm [1,0,3,2]  : lane ^= 1
#define XOR2 0x4E   // quad_perm [2,3,0,1]  : lane ^= 2
#define XOR8 0x128  // row_ror:8            : lane ^= 8 (within 16-lane row)

// Padded LDS offset for hidden unit u: 16-float slices at stride 20.
// Slice s starts at s*20 -> banks {0,20,8,28,16,4,24,12}+chunk: conflict-free.
__device__ __forceinline__ int uoff(int u) { return (u >> 4) * 20 + (u & 15); }

// ---------------------------------------------------------------------------
// Single fused kernel. 256 blocks x 512 threads (8 waves, 2/SIMD, 1 block/CU).
//   S0 (tid   0..127, 2 waves): h0_k = tanh(Wih0.x_k + b0 + Whh0.h0_{k-1})
//   P  (tid 128..383, 4 waves): B_{k-1} = Wih1.h0_{k-1} + b1
//   S1 (tid 384..511, 2 waves): h1_{k-2} = tanh(B_{k-2} + Whh1.h1_{k-3})
// Slice layout (traffic-optimal, R1 lesson): S0/S1 thread owns 8 units x
// 16-float slice (128 weight VGPRs, 16 LDS floats/step). Unit-group = the
// xor-closed lane set {0-3,8-11} within a 16-lane row, so the 3-level
// reduction uses masks {1,2,8} — ALL DPP (quad_perm, quad_perm, row_ror:8),
// zero LDS-pipe ops on the serial recurrence chain.
// pre0 fused: S0 double-buffers x in 8-step LDS chunks (loaded 2 ahead) and
// computes the 19-FMA input projection for its finalized unit at step-top
// (independent of h -> off the critical chain).
// s_setprio(1) on S0/S1 (chain-critical); P (slack) stays 0. SIMD pairing:
// {S0,P},{S0,P},{P,S1},{P,S1}. All groups execute 1027 barriers.
// ---------------------------------------------------------------------------
__global__ __launch_bounds__(512, 2)
void fused_rnn(const float* __restrict__ x,      // [B,T,IN]
               const float* __restrict__ Wih0,   // [H,IN]
               const float* __restrict__ Whh0,   // [H,H]
               const float* __restrict__ bih0,
               const float* __restrict__ bhh0,
               const float* __restrict__ Wih1,   // [H,H]
               const float* __restrict__ Whh1,   // [H,H]
               const float* __restrict__ bih1,
               const float* __restrict__ bhh1,
               float* __restrict__ out) {        // [B,T,H]
    const int b   = blockIdx.x;
    const int tid = threadIdx.x;

    __shared__ __align__(16) float h0ring[4][160];
    __shared__ __align__(16) float h1ring[4][160];
    __shared__ __align__(16) float Bring[4][H];
    // x chunks: 8 steps x 19 floats, padded to stride 20 (pad zeroed once;
    // wI[19]=0 so the pad lane contributes 0).
    __shared__ __align__(16) float xbuf[2][8 * 20];

    if (tid < 128) {
        // =================== S0 ===================
        __builtin_amdgcn_s_setprio(1);
        const bool b0 = tid & 1, b1 = tid & 2, b2 = tid & 8;
        const int s    = (tid & 3) | ((tid & 8) >> 1);          // slice 0..7
        const int G    = (tid >> 4) * 2 + ((tid >> 2) & 1);     // group 0..15
        const int ub   = G * 8;
        const int ufin = ub + (b0 ? 4 : 0) + (b1 ? 2 : 0) + (b2 ? 1 : 0);

        float wA[8][16];
#pragma unroll
        for (int u = 0; u < 8; ++u) {
            const float* wr = Whh0 + (size_t)(ub + u) * H + s * 16;
#pragma unroll
            for (int c = 0; c < 16; c += 4) {
                float4 v = *(const float4*)&wr[c];
                wA[u][c] = v.x; wA[u][c+1] = v.y; wA[u][c+2] = v.z; wA[u][c+3] = v.w;
            }
        }
        float wI[20];
#pragma unroll
        for (int f = 0; f < IN; ++f) wI[f] = Wih0[ufin * IN + f];
        wI[19] = 0.0f;
        const float bias0 = bih0[ufin] + bhh0[ufin];

        // x staging: chunk = 8*IN = 152 elements; thread loads idx0=tid and
        // (tid<24) idx1=tid+128. Scatter into stride-20 slots.
        const float* xsrc = x + (size_t)b * T * IN;
        const int idx0  = tid;
        const int idx1  = tid + 128;
        const bool v1   = (idx1 < 8 * IN);
        const int slot0 = (idx0 / IN) * 20 + idx0 % IN;
        const int slot1 = (idx1 / IN) * 20 + idx1 % IN;

        if (tid < 8) { xbuf[0][tid * 20 + 19] = 0.0f; xbuf[1][tid * 20 + 19] = 0.0f; }
        xbuf[0][slot0] = xsrc[idx0];
        if (v1) xbuf[0][slot1] = xsrc[idx1];
        float xr0 = xsrc[8 * IN + idx0];
        float xr1 = v1 ? xsrc[8 * IN + idx1] : 0.0f;

        h0ring[3][uoff(ufin)] = 0.0f;   // h0_{-1}
        __syncthreads();                 // init barrier

        const int so = s * 20;
        const int wo = uoff(ufin);
        for (int ko = 0; ko < T; ko += 8) {
            const int cb = (ko >> 3) & 1;
            const float* xch = xbuf[cb];
#pragma unroll
            for (int j = 0; j < 8; ++j) {
                // ---- input projection (independent of h: fills early slots)
                const float* xp = &xch[j * 20];
                float4 xv0 = *(const float4*)&xp[0];
                float4 xv1 = *(const float4*)&xp[4];
                float4 xv2 = *(const float4*)&xp[8];
                float4 xv3 = *(const float4*)&xp[12];
                float4 xv4 = *(const float4*)&xp[16];   // .w = pad (0 weight)
                float p0 = bias0, p1 = 0.0f;
                p0 = fmaf(xv0.x, wI[0],  p0); p1 = fmaf(xv0.y, wI[1],  p1);
                p0 = fmaf(xv0.z, wI[2],  p0); p1 = fmaf(xv0.w, wI[3],  p1);
                p0 = fmaf(xv1.x, wI[4],  p0); p1 = fmaf(xv1.y, wI[5],  p1);
                p0 = fmaf(xv1.z, wI[6],  p0); p1 = fmaf(xv1.w, wI[7],  p1);
                p0 = fmaf(xv2.x, wI[8],  p0); p1 = fmaf(xv2.y, wI[9],  p1);
                p0 = fmaf(xv2.z, wI[10], p0); p1 = fmaf(xv2.w, wI[11], p1);
                p0 = fmaf(xv3.x, wI[12], p0); p1 = fmaf(xv3.y, wI[13], p1);
                p0 = fmaf(xv3.z, wI[14], p0); p1 = fmaf(xv3.w, wI[15], p1);
                p0 = fmaf(xv4.x, wI[16], p0); p1 = fmaf(xv4.y, wI[17], p1);
                p0 = fmaf(xv4.z, wI[18], p0); p1 = fmaf(xv4.w, wI[19], p1);
                // ---- recurrent dot: 8 units x 16-slice ----
                const float* hp = &h0ring[(j + 3) & 3][so];
                float d0=0,d1=0,d2=0,d3=0,d4=0,d5=0,d6=0,d7=0;
#pragma unroll
                for (int c = 0; c < 16; c += 4) {
                    float4 hv = *(const float4*)&hp[c];
                    d0 = fmaf(wA[0][c],hv.x,d0); d0 = fmaf(wA[0][c+1],hv.y,d0); d0 = fmaf(wA[0][c+2],hv.z,d0); d0 = fmaf(wA[0][c+3],hv.w,d0);
                    d1 = fmaf(wA[1][c],hv.x,d1); d1 = fmaf(wA[1][c+1],hv.y,d1); d1 = fmaf(wA[1][c+2],hv.z,d1); d1 = fmaf(wA[1][c+3],hv.w,d1);
                    d2 = fmaf(wA[2][c],hv.x,d2); d2 = fmaf(wA[2][c+1],hv.y,d2); d2 = fmaf(wA[2][c+2],hv.z,d2); d2 = fmaf(wA[2][c+3],hv.w,d2);
                    d3 = fmaf(wA[3][c],hv.x,d3); d3 = fmaf(wA[3][c+1],hv.y,d3); d3 = fmaf(wA[3][c+2],hv.z,d3); d3 = fmaf(wA[3][c+3],hv.w,d3);
                    d4 = fmaf(wA[4][c],hv.x,d4); d4 = fmaf(wA[4][c+1],hv.y,d4); d4 = fmaf(wA[4][c+2],hv.z,d4); d4 = fmaf(wA[4][c+3],hv.w,d4);
                    d5 = fmaf(wA[5][c],hv.x,d5); d5 = fmaf(wA[5][c+1],hv.y,d5); d5 = fmaf(wA[5][c+2],hv.z,d5); d5 = fmaf(wA[5][c+3],hv.w,d5);
                    d6 = fmaf(wA[6][c],hv.x,d6); d6 = fmaf(wA[6][c+1],hv.y,d6); d6 = fmaf(wA[6][c+2],hv.z,d6); d6 = fmaf(wA[6][c+3],hv.w,d6);
                    d7 = fmaf(wA[7][c],hv.x,d7); d7 = fmaf(wA[7][c+1],hv.y,d7); d7 = fmaf(wA[7][c+2],hv.z,d7); d7 = fmaf(wA[7][c+3],hv.w,d7);
                }
                // ---- 3-level DPP reduce (masks 1,2,8) ----
                float e0 = (b0 ? d4 : d0) + dppf<XOR1>(b0 ? d0 : d4);
                float e1 = (b0 ? d5 : d1) + dppf<XOR1>(b0 ? d1 : d5);
                float e2 = (b0 ? d6 : d2) + dppf<XOR1>(b0 ? d2 : d6);
                float e3 = (b0 ? d7 : d3) + dppf<XOR1>(b0 ? d3 : d7);
                float g0 = (b1 ? e2 : e0) + dppf<XOR2>(b1 ? e0 : e2);
                float g1 = (b1 ? e3 : e1) + dppf<XOR2>(b1 ? e1 : e3);
                float f  = (b2 ? g1 : g0) + dppf<XOR8>(b2 ? g0 : g1);
                h0ring[j & 3][wo] = fast_tanh(f + p0 + p1);
                if (j == 7) {
                    if (ko + 8 < T) {       // publish next chunk (pre-barrier)
                        float* xd = xbuf[cb ^ 1];
                        xd[slot0] = xr0;
                        if (v1) xd[slot1] = xr1;
                    }
                    if (ko + 16 < T) {      // fetch chunk+2 (8 intervals cover)
                        const float* xs2 = xsrc + (size_t)(ko + 16) * IN;
                        xr0 = xs2[idx0];
                        if (v1) xr1 = xs2[idx1];
                    }
                }
                __syncthreads();
            }
        }
        __syncthreads();   // interval 1024
        __syncthreads();   // interval 1025
    } else if (tid < 384) {
        // =================== P ===================
        const int p  = tid - 128;
        const bool b0 = p & 1, b1 = p & 2;
        const int s    = (p & 3) | ((p & 8) >> 1);            // slice 0..7
        const int Gp   = (p >> 4) * 2 + ((p >> 2) & 1);       // group 0..31
        const int ub   = Gp * 4;
        const int ufin = ub + (b0 ? 2 : 0) + (b1 ? 1 : 0);

        float wP[4][16];
#pragma unroll
        for (int u = 0; u < 4; ++u) {
            const float* wr = Wih1 + (size_t)(ub + u) * H + s * 16;
#pragma unroll
            for (int c = 0; c < 16; c += 4) {
                float4 v = *(const float4*)&wr[c];
                wP[u][c] = v.x; wP[u][c+1] = v.y; wP[u][c+2] = v.z; wP[u][c+3] = v.w;
            }
        }
        const float biasP = bih1[ufin] + bhh1[ufin];

        __syncthreads();   // init barrier
        __syncthreads();   // interval 0 (no work)

        const int so = s * 20;
        for (int ko = 1; ko < 1025; ko += 8) {
#pragma unroll
            for (int j = 0; j < 8; ++j) {
                // (k+3)&3 with ko%8==1  ->  j&3
                const float* hp = &h0ring[j & 3][so];
                float d0=0,d1=0,d2=0,d3=0;
#pragma unroll
                for (int c = 0; c < 16; c += 4) {
                    float4 hv = *(const float4*)&hp[c];
                    d0 = fmaf(wP[0][c],hv.x,d0); d0 = fmaf(wP[0][c+1],hv.y,d0); d0 = fmaf(wP[0][c+2],hv.z,d0); d0 = fmaf(wP[0][c+3],hv.w,d0);
                    d1 = fmaf(wP[1][c],hv.x,d1); d1 = fmaf(wP[1][c+1],hv.y,d1); d1 = fmaf(wP[1][c+2],hv.z,d1); d1 = fmaf(wP[1][c+3],hv.w,d1);
                    d2 = fmaf(wP[2][c],hv.x,d2); d2 = fmaf(wP[2][c+1],hv.y,d2); d2 = fmaf(wP[2][c+2],hv.z,d2); d2 = fmaf(wP[2][c+3],hv.w,d2);
                    d3 = fmaf(wP[3][c],hv.x,d3); d3 = fmaf(wP[3][c+1],hv.y,d3); d3 = fmaf(wP[3][c+2],hv.z,d3); d3 = fmaf(wP[3][c+3],hv.w,d3);
                }
                float e0 = (b0 ? d2 : d0) + dppf<XOR1>(b0 ? d0 : d2);
                float e1 = (b0 ? d3 : d1) + dppf<XOR1>(b0 ? d1 : d3);
                float g  = (b1 ? e1 : e0) + dppf<XOR2>(b1 ? e0 : e1);
                g += dppf<XOR8>(g);
                if (!(p & 8)) Bring[j & 3][ufin] = g + biasP;
                __syncthreads();
            }
        }
        __syncthreads();   // interval 1025
    } else {
        // =================== S1 ===================
        __builtin_amdgcn_s_setprio(1);
        const int w  = tid - 384;
        const bool b0 = w & 1, b1 = w & 2, b2 = w & 8;
        const int s    = (w & 3) | ((w & 8) >> 1);
        const int G    = (w >> 4) * 2 + ((w >> 2) & 1);
        const int ub   = G * 8;
        const int ufin = ub + (b0 ? 4 : 0) + (b1 ? 2 : 0) + (b2 ? 1 : 0);

        float wA[8][16];
#pragma unroll
        for (int u = 0; u < 8; ++u) {
            const float* wr = Whh1 + (size_t)(ub + u) * H + s * 16;
#pragma unroll
            for (int c = 0; c < 16; c += 4) {
                float4 v = *(const float4*)&wr[c];
                wA[u][c] = v.x; wA[u][c+1] = v.y; wA[u][c+2] = v.z; wA[u][c+3] = v.w;
            }
        }
        float* orow = out + (size_t)b * T * H + ufin;
        float sbuf[8];

        h1ring[3][uoff(ufin)] = 0.0f;   // h1_{-1}
        __syncthreads();   // init barrier
        __syncthreads();   // interval 0
        __syncthreads();   // interval 1

        const int so = s * 20;
        const int wo = uoff(ufin);
        for (int ko = 2; ko < 1026; ko += 8) {
#pragma unroll
            for (int j = 0; j < 8; ++j) {
                // ko%8==2: (k+1)&3 -> (j+3)&3 ; (k+2)&3 -> j&3
                const float* hp = &h1ring[(j + 3) & 3][so];
                float Bg = Bring[j & 3][ufin];
                float d0=0,d1=0,d2=0,d3=0,d4=0,d5=0,d6=0,d7=0;
#pragma unroll
                for (int c = 0; c < 16; c += 4) {
                    float4 hv = *(const float4*)&hp[c];
                    d0 = fmaf(wA[0][c],hv.x,d0); d0 = fmaf(wA[0][c+1],hv.y,d0); d0 = fmaf(wA[0][c+2],hv.z,d0); d0 = fmaf(wA[0][c+3],hv.w,d0);
                    d1 = fmaf(wA[1][c],hv.x,d1); d1 = fmaf(wA[1][c+1],hv.y,d1); d1 = fmaf(wA[1][c+2],hv.z,d1); d1 = fmaf(wA[1][c+3],hv.w,d1);
                    d2 = fmaf(wA[2][c],hv.x,d2); d2 = fmaf(wA[2][c+1],hv.y,d2); d2 = fmaf(wA[2][c+2],hv.z,d2); d2 = fmaf(wA[2][c+3],hv.w,d2);
                    d3 = fmaf(wA[3][c],hv.x,d3); d3 = fmaf(wA[3][c+1],hv.y,d3); d3 = fmaf(wA[3][c+2],hv.z,d3); d3 = fmaf(wA[3][c+3],hv.w,d3);
                    d4 = fmaf(wA[4][c],hv.x,d4); d4 = fmaf(wA[4][c+1],hv.y,d4); d4 = fmaf(wA[4][c+2],hv.z,d4); d4 = fmaf(wA[4][c+3],hv.w,d4);
                    d5 = fmaf(wA[5][c],hv.x,d5); d5 = fmaf(wA[5][c+1],hv.y,d5); d5 = fmaf(wA[5][c+2],hv.z,d5); d5 = fmaf(wA[5][c+3],hv.w,d5);
                    d6 = fmaf(wA[6][c],hv.x,d6); d6 = fmaf(wA[6][c+1],hv.y,d6); d6 = fmaf(wA[6][c+2],hv.z,d6); d6 = fmaf(wA[6][c+3],hv.w,d6);
                    d7 = fmaf(wA[7][c],hv.x,d7); d7 = fmaf(wA[7][c+1],hv.y,d7); d7 = fmaf(wA[7][c+2],hv.z,d7); d7 = fmaf(wA[7][c+3],hv.w,d7);
                }
                float e0 = (b0 ? d4 : d0) + dppf<XOR1>(b0 ? d0 : d4);
                float e1 = (b0 ? d5 : d1) + dppf<XOR1>(b0 ? d1 : d5);
                float e2 = (b0 ? d6 : d2) + dppf<XOR1>(b0 ? d2 : d6);
                float e3 = (b0 ? d7 : d3) + dppf<XOR1>(b0 ? d3 : d7);
                float g0 = (b1 ? e2 : e0) + dppf<XOR2>(b1 ? e0 : e2);
                float g1 = (b1 ? e3 : e1) + dppf<XOR2>(b1 ? e1 : e3);
                float f  = (b2 ? g1 : g0) + dppf<XOR8>(b2 ? g0 : g1);
                float h1v = fast_tanh(Bg + f);
                h1ring[j & 3][wo] = h1v;
                sbuf[j] = h1v;
                if (j == 7) {                  // burst-write t = ko-2 .. ko+5
                    const int t0 = ko - 2;
#pragma unroll
                    for (int i = 0; i < 8; ++i)
                        orow[(size_t)(t0 + i) * H] = sbuf[i];
                }
                __syncthreads();
            }
        }
        // no trailing barriers needed for S1 (last interval is 1025)
    }
}

// ---------------------------------------------------------------------------
extern "C" void kernel_launch(void* const* d_in, const int* in_sizes, int n_in,
                              void* d_out, int out_size, void* d_ws, size_t ws_size,
                              hipStream_t stream) {
    const float* x     = (const float*)d_in[0];
    const float* W_ih0 = (const float*)d_in[1];
    const float* W_hh0 = (const float*)d_in[2];
    const float* b_ih0 = (const float*)d_in[3];
    const float* b_hh0 = (const float*)d_in[4];
    const float* W_ih1 = (const float*)d_in[5];
    const float* W_hh1 = (const float*)d_in[6];
    const float* b_ih1 = (const float*)d_in[7];
    const float* b_hh1 = (const float*)d_in[8];

    float* out = (float*)d_out;

    fused_rnn<<<BATCH, 512, 0, stream>>>(x, W_ih0, W_hh0, b_ih0, b_hh0,
                                         W_ih1, W_hh1, b_ih1, b_hh1, out);
}

// Round 5
// 608.664 us; speedup vs baseline: 1.8991x; 1.0822x over previous
//
#include <hip/hip_runtime.h>
#include <math.h>

#define BATCH 256
#define T 1024
#define IN 19
#define H 128

// tanh via v_exp_f32: tanh(x)=sign(x)*(1-2/(exp(2|x|)+1)); exact to ~1e-7.
__device__ __forceinline__ float fast_tanh(float x) {
    float ax = fabsf(x);
    float e  = __expf(2.0f * ax);
    float r  = 1.0f - 2.0f / (e + 1.0f);
    return copysignf(r, x);
}

// DPP cross-lane move (VALU-only, no LDS pipe).
template <int CTRL>
__device__ __forceinline__ float dppf(float v) {
    return __int_as_float(__builtin_amdgcn_update_dpp(
        0, __float_as_int(v), CTRL, 0xF, 0xF, true));
}
#define XOR1 0xB1   // quad_perm [1,0,3,2]  : lane ^= 1
#define XOR2 0x4E   // quad_perm [2,3,0,1]  : lane ^= 2
#define XOR8 0x128  // row_ror:8            : lane ^= 8 (within 16-lane row)

// Lightweight barrier: waits LDS only (NO vmcnt drain — global loads/stores
// stay in flight across steps). asm memory-clobber pair fences compiler
// code motion on both sides of s_barrier.
__device__ __forceinline__ void sync_fast() {
    asm volatile("s_waitcnt lgkmcnt(0)" ::: "memory");
    __builtin_amdgcn_s_barrier();
    asm volatile("" ::: "memory");
}

// Padded LDS offset for hidden unit u: 16-float slices at stride 20.
__device__ __forceinline__ int uoff(int u) { return (u >> 4) * 20 + (u & 15); }

// ---------------------------------------------------------------------------
// Single fused kernel. 256 blocks x 512 threads (8 waves, 2/SIMD, 1 block/CU).
//   S0 (tid   0..127, 2 waves): h0_k = tanh(proj0_k + Whh0.h0_{k-1})
//   P  (tid 128..383, 4 waves): B_{k-1} = Wih1.h0_{k-1} + b1
//                               waves 4-5 (p>=128) also: proj0_{k+1}
//   S1 (tid 384..511, 2 waves): h1_{k-2} = tanh(B_{k-2} + Whh1.h1_{k-3})
// vs R2: (a) raw s_barrier (no per-step vmcnt(0) drain); (b) input projection
// + x staging moved from S0 to P (proj ring, 1 interval ahead) so S0's serial
// chain is pure recurrence; (c) proj duty on waves 4/5 -> SIMD pairing
// {S0,P-proj} x2 + {P-plain,S1} x2, issue-balanced.
// R4 bug fixed: P's loop (intervals 0..1023) computes B_{-1}..B_1022 only;
// B_1023 now computed in a P epilogue during interval 1024 (h0_1023 is in
// slot 3, written at interval 1023; S1 reads Bring[3] at interval 1025).
// All groups execute exactly 1027 barriers.
// ---------------------------------------------------------------------------
__global__ __launch_bounds__(512, 2)
void fused_rnn(const float* __restrict__ x,      // [B,T,IN]
               const float* __restrict__ Wih0,   // [H,IN]
               const float* __restrict__ Whh0,   // [H,H]
               const float* __restrict__ bih0,
               const float* __restrict__ bhh0,
               const float* __restrict__ Wih1,   // [H,H]
               const float* __restrict__ Whh1,   // [H,H]
               const float* __restrict__ bih1,
               const float* __restrict__ bhh1,
               float* __restrict__ out) {        // [B,T,H]
    const int b   = blockIdx.x;
    const int tid = threadIdx.x;

    __shared__ __align__(16) float h0ring[4][160];
    __shared__ __align__(16) float h1ring[4][160];
    __shared__ __align__(16) float Bring[4][H];
    __shared__ __align__(16) float projring[4][H];   // proj0 for step k at [k&3]
    // x chunks: 8 steps x 19 floats, stride 20. Chunk c holds rows 8c+1..8c+8
    // (+1 shift: proj at interval k targets step k+1).
    __shared__ __align__(16) float xbuf[2][8 * 20];

    if (tid < 128) {
        // =================== S0 (pure recurrence) ===================
        __builtin_amdgcn_s_setprio(1);
        const bool b0 = tid & 1, b1 = tid & 2, b2 = tid & 8;
        const int s    = (tid & 3) | ((tid & 8) >> 1);          // slice 0..7
        const int G    = (tid >> 4) * 2 + ((tid >> 2) & 1);     // group 0..15
        const int ub   = G * 8;
        const int ufin = ub + (b0 ? 4 : 0) + (b1 ? 2 : 0) + (b2 ? 1 : 0);

        float wA[8][16];
#pragma unroll
        for (int u = 0; u < 8; ++u) {
            const float* wr = Whh0 + (size_t)(ub + u) * H + s * 16;
#pragma unroll
            for (int c = 0; c < 16; c += 4) {
                float4 v = *(const float4*)&wr[c];
                wA[u][c] = v.x; wA[u][c+1] = v.y; wA[u][c+2] = v.z; wA[u][c+3] = v.w;
            }
        }
        // prologue: proj_0 self-computed (P's ring starts at proj_1)
        {
            const float* wr = Wih0 + ufin * IN;
            const float* xr = x + (size_t)b * T * IN;   // row 0
            float acc = bih0[ufin] + bhh0[ufin];
#pragma unroll
            for (int f = 0; f < IN; ++f) acc = fmaf(xr[f], wr[f], acc);
            projring[0][ufin] = acc;
        }
        h0ring[3][uoff(ufin)] = 0.0f;   // h0_{-1}
        sync_fast();                     // init barrier

        const int so = s * 20;
        const int wo = uoff(ufin);
        for (int ko = 0; ko < T; ko += 8) {
#pragma unroll
            for (int j = 0; j < 8; ++j) {
                const float* hp = &h0ring[(j + 3) & 3][so];
                float pcur = projring[j & 3][ufin];
                float d0=0,d1=0,d2=0,d3=0,d4=0,d5=0,d6=0,d7=0;
#pragma unroll
                for (int c = 0; c < 16; c += 4) {
                    float4 hv = *(const float4*)&hp[c];
                    d0 = fmaf(wA[0][c],hv.x,d0); d0 = fmaf(wA[0][c+1],hv.y,d0); d0 = fmaf(wA[0][c+2],hv.z,d0); d0 = fmaf(wA[0][c+3],hv.w,d0);
                    d1 = fmaf(wA[1][c],hv.x,d1); d1 = fmaf(wA[1][c+1],hv.y,d1); d1 = fmaf(wA[1][c+2],hv.z,d1); d1 = fmaf(wA[1][c+3],hv.w,d1);
                    d2 = fmaf(wA[2][c],hv.x,d2); d2 = fmaf(wA[2][c+1],hv.y,d2); d2 = fmaf(wA[2][c+2],hv.z,d2); d2 = fmaf(wA[2][c+3],hv.w,d2);
                    d3 = fmaf(wA[3][c],hv.x,d3); d3 = fmaf(wA[3][c+1],hv.y,d3); d3 = fmaf(wA[3][c+2],hv.z,d3); d3 = fmaf(wA[3][c+3],hv.w,d3);
                    d4 = fmaf(wA[4][c],hv.x,d4); d4 = fmaf(wA[4][c+1],hv.y,d4); d4 = fmaf(wA[4][c+2],hv.z,d4); d4 = fmaf(wA[4][c+3],hv.w,d4);
                    d5 = fmaf(wA[5][c],hv.x,d5); d5 = fmaf(wA[5][c+1],hv.y,d5); d5 = fmaf(wA[5][c+2],hv.z,d5); d5 = fmaf(wA[5][c+3],hv.w,d5);
                    d6 = fmaf(wA[6][c],hv.x,d6); d6 = fmaf(wA[6][c+1],hv.y,d6); d6 = fmaf(wA[6][c+2],hv.z,d6); d6 = fmaf(wA[6][c+3],hv.w,d6);
                    d7 = fmaf(wA[7][c],hv.x,d7); d7 = fmaf(wA[7][c+1],hv.y,d7); d7 = fmaf(wA[7][c+2],hv.z,d7); d7 = fmaf(wA[7][c+3],hv.w,d7);
                }
                float e0 = (b0 ? d4 : d0) + dppf<XOR1>(b0 ? d0 : d4);
                float e1 = (b0 ? d5 : d1) + dppf<XOR1>(b0 ? d1 : d5);
                float e2 = (b0 ? d6 : d2) + dppf<XOR1>(b0 ? d2 : d6);
                float e3 = (b0 ? d7 : d3) + dppf<XOR1>(b0 ? d3 : d7);
                float g0 = (b1 ? e2 : e0) + dppf<XOR2>(b1 ? e0 : e2);
                float g1 = (b1 ? e3 : e1) + dppf<XOR2>(b1 ? e1 : e3);
                float f  = (b2 ? g1 : g0) + dppf<XOR8>(b2 ? g0 : g1);
                h0ring[j & 3][wo] = fast_tanh(pcur + f);
                sync_fast();
            }
        }
        sync_fast();   // interval 1024
        sync_fast();   // interval 1025
    } else if (tid < 384) {
        // =================== P (B-projection + layer-0 input projection) ====
        const int p  = tid - 128;
        const bool b0 = p & 1, b1 = p & 2;
        const int s    = (p & 3) | ((p & 8) >> 1);            // slice 0..7
        const int Gp   = (p >> 4) * 2 + ((p >> 2) & 1);       // group 0..31
        const int ub   = Gp * 4;
        const int ufin = ub + (b0 ? 2 : 0) + (b1 ? 1 : 0);

        float wP[4][16];
#pragma unroll
        for (int u = 0; u < 4; ++u) {
            const float* wr = Wih1 + (size_t)(ub + u) * H + s * 16;
#pragma unroll
            for (int c = 0; c < 16; c += 4) {
                float4 v = *(const float4*)&wr[c];
                wP[u][c] = v.x; wP[u][c+1] = v.y; wP[u][c+2] = v.z; wP[u][c+3] = v.w;
            }
        }
        const float biasP = bih1[ufin] + bhh1[ufin];

        // ---- proj duty: waves 4-5 (p>=128), unit = p-128 ----
        // (waves 4/5 share SIMD0/1 with S0 — the lightest recurrence wave)
        const bool hasProj = (p >= 128);
        const int pu = p - 128;                        // proj unit 0..127
        float wIP[20];
        float biasPr = 0.0f;
        const float* xsrc = x + (size_t)b * T * IN + IN;   // row 1 base
        const int idx0  = pu;
        const int idx1  = pu + 128;
        const bool v1   = hasProj && (pu < 24);
        const int slot0 = hasProj ? ((idx0 / IN) * 20 + idx0 % IN) : 0;
        const int slot1 = hasProj ? ((idx1 / IN) * 20 + idx1 % IN) : 0;
        const int XMAX  = (T - 1) * IN - 1;                // last elem rel to xsrc
        float xr0 = 0.0f, xr1 = 0.0f;

        if (hasProj) {
            const float* wr = Wih0 + (size_t)pu * IN;
#pragma unroll
            for (int f = 0; f < IN; ++f) wIP[f] = wr[f];
            wIP[19] = 0.0f;
            biasPr = bih0[pu] + bhh0[pu];
            if (pu < 8) { xbuf[0][pu * 20 + 19] = 0.0f; xbuf[1][pu * 20 + 19] = 0.0f; }
            // chunk 0 -> LDS, chunk 1 -> regs
            xbuf[0][slot0] = xsrc[idx0];
            if (v1) xbuf[0][slot1] = xsrc[idx1];
            xr0 = xsrc[152 + idx0];
            if (v1) xr1 = xsrc[152 + idx1];
        }
        sync_fast();   // init barrier

        const int so = s * 20;
        for (int ko = 0; ko < T; ko += 8) {
            const int cb = (ko >> 3) & 1;
#pragma unroll
            for (int j = 0; j < 8; ++j) {
                // ---- B_{k-1}: dot over h0_{k-1} (slot (j+3)&3) ----
                const float* hp = &h0ring[(j + 3) & 3][so];
                float d0=0,d1=0,d2=0,d3=0;
#pragma unroll
                for (int c = 0; c < 16; c += 4) {
                    float4 hv = *(const float4*)&hp[c];
                    d0 = fmaf(wP[0][c],hv.x,d0); d0 = fmaf(wP[0][c+1],hv.y,d0); d0 = fmaf(wP[0][c+2],hv.z,d0); d0 = fmaf(wP[0][c+3],hv.w,d0);
                    d1 = fmaf(wP[1][c],hv.x,d1); d1 = fmaf(wP[1][c+1],hv.y,d1); d1 = fmaf(wP[1][c+2],hv.z,d1); d1 = fmaf(wP[1][c+3],hv.w,d1);
                    d2 = fmaf(wP[2][c],hv.x,d2); d2 = fmaf(wP[2][c+1],hv.y,d2); d2 = fmaf(wP[2][c+2],hv.z,d2); d2 = fmaf(wP[2][c+3],hv.w,d2);
                    d3 = fmaf(wP[3][c],hv.x,d3); d3 = fmaf(wP[3][c+1],hv.y,d3); d3 = fmaf(wP[3][c+2],hv.z,d3); d3 = fmaf(wP[3][c+3],hv.w,d3);
                }
                float e0 = (b0 ? d2 : d0) + dppf<XOR1>(b0 ? d0 : d2);
                float e1 = (b0 ? d3 : d1) + dppf<XOR1>(b0 ? d1 : d3);
                float g  = (b1 ? e1 : e0) + dppf<XOR2>(b1 ? e0 : e1);
                g += dppf<XOR8>(g);
                if (!(p & 8)) Bring[(j + 3) & 3][ufin] = g + biasP;
                // ---- proj0_{k+1} from x row j of current chunk ----
                if (hasProj) {
                    const float* xp = &xbuf[cb][j * 20];
                    float4 xv0 = *(const float4*)&xp[0];
                    float4 xv1 = *(const float4*)&xp[4];
                    float4 xv2 = *(const float4*)&xp[8];
                    float4 xv3 = *(const float4*)&xp[12];
                    float4 xv4 = *(const float4*)&xp[16];   // .w = pad
                    float p0 = biasPr, p1 = 0.0f;
                    p0 = fmaf(xv0.x, wIP[0],  p0); p1 = fmaf(xv0.y, wIP[1],  p1);
                    p0 = fmaf(xv0.z, wIP[2],  p0); p1 = fmaf(xv0.w, wIP[3],  p1);
                    p0 = fmaf(xv1.x, wIP[4],  p0); p1 = fmaf(xv1.y, wIP[5],  p1);
                    p0 = fmaf(xv1.z, wIP[6],  p0); p1 = fmaf(xv1.w, wIP[7],  p1);
                    p0 = fmaf(xv2.x, wIP[8],  p0); p1 = fmaf(xv2.y, wIP[9],  p1);
                    p0 = fmaf(xv2.z, wIP[10], p0); p1 = fmaf(xv2.w, wIP[11], p1);
                    p0 = fmaf(xv3.x, wIP[12], p0); p1 = fmaf(xv3.y, wIP[13], p1);
                    p0 = fmaf(xv3.z, wIP[14], p0); p1 = fmaf(xv3.w, wIP[15], p1);
                    p0 = fmaf(xv4.x, wIP[16], p0); p1 = fmaf(xv4.y, wIP[17], p1);
                    p0 = fmaf(xv4.z, wIP[18], p0); p1 = fmaf(xv4.w, wIP[19], p1);
                    projring[(j + 1) & 3][pu] = p0 + p1;
                    if (j == 7) {
                        // publish chunk c+1 (pre-barrier), fetch chunk c+2
                        float* xd = xbuf[cb ^ 1];
                        xd[slot0] = xr0;
                        if (v1) xd[slot1] = xr1;
                        const int c2 = (ko >> 3) + 2;
                        int o0 = 152 * c2 + idx0; o0 = o0 > XMAX ? XMAX : o0;
                        int o1 = 152 * c2 + idx1; o1 = o1 > XMAX ? XMAX : o1;
                        xr0 = xsrc[o0];
                        if (v1) xr1 = xsrc[o1];
                    }
                }
                sync_fast();
            }
        }
        // ---- epilogue (interval 1024): B_1023 from h0_1023 (slot 3) ----
        // R4 bug fix: loop intervals 0..1023 produce B_{-1}..B_1022 only;
        // S1 needs B_1023 at interval 1025 from Bring[3].
        {
            const float* hp = &h0ring[3][so];
            float d0=0,d1=0,d2=0,d3=0;
#pragma unroll
            for (int c = 0; c < 16; c += 4) {
                float4 hv = *(const float4*)&hp[c];
                d0 = fmaf(wP[0][c],hv.x,d0); d0 = fmaf(wP[0][c+1],hv.y,d0); d0 = fmaf(wP[0][c+2],hv.z,d0); d0 = fmaf(wP[0][c+3],hv.w,d0);
                d1 = fmaf(wP[1][c],hv.x,d1); d1 = fmaf(wP[1][c+1],hv.y,d1); d1 = fmaf(wP[1][c+2],hv.z,d1); d1 = fmaf(wP[1][c+3],hv.w,d1);
                d2 = fmaf(wP[2][c],hv.x,d2); d2 = fmaf(wP[2][c+1],hv.y,d2); d2 = fmaf(wP[2][c+2],hv.z,d2); d2 = fmaf(wP[2][c+3],hv.w,d2);
                d3 = fmaf(wP[3][c],hv.x,d3); d3 = fmaf(wP[3][c+1],hv.y,d3); d3 = fmaf(wP[3][c+2],hv.z,d3); d3 = fmaf(wP[3][c+3],hv.w,d3);
            }
            float e0 = (b0 ? d2 : d0) + dppf<XOR1>(b0 ? d0 : d2);
            float e1 = (b0 ? d3 : d1) + dppf<XOR1>(b0 ? d1 : d3);
            float g  = (b1 ? e1 : e0) + dppf<XOR2>(b1 ? e0 : e1);
            g += dppf<XOR8>(g);
            if (!(p & 8)) Bring[3][ufin] = g + biasP;
        }
        sync_fast();   // interval 1024
        sync_fast();   // interval 1025
    } else {
        // =================== S1 ===================
        __builtin_amdgcn_s_setprio(1);
        const int w  = tid - 384;
        const bool b0 = w & 1, b1 = w & 2, b2 = w & 8;
        const int s    = (w & 3) | ((w & 8) >> 1);
        const int G    = (w >> 4) * 2 + ((w >> 2) & 1);
        const int ub   = G * 8;
        const int ufin = ub + (b0 ? 4 : 0) + (b1 ? 2 : 0) + (b2 ? 1 : 0);

        float wA[8][16];
#pragma unroll
        for (int u = 0; u < 8; ++u) {
            const float* wr = Whh1 + (size_t)(ub + u) * H + s * 16;
#pragma unroll
            for (int c = 0; c < 16; c += 4) {
                float4 v = *(const float4*)&wr[c];
                wA[u][c] = v.x; wA[u][c+1] = v.y; wA[u][c+2] = v.z; wA[u][c+3] = v.w;
            }
        }
        float* orow = out + (size_t)b * T * H + ufin;
        float sbuf[8];

        h1ring[3][uoff(ufin)] = 0.0f;   // h1_{-1}
        sync_fast();   // init barrier
        sync_fast();   // interval 0
        sync_fast();   // interval 1

        const int so = s * 20;
        const int wo = uoff(ufin);
        for (int ko = 2; ko < 1026; ko += 8) {
#pragma unroll
            for (int j = 0; j < 8; ++j) {
                // ko%8==2: h1_{t-1} slot -> (j+3)&3 ; B_{k-2} slot -> j&3
                const float* hp = &h1ring[(j + 3) & 3][so];
                float Bg = Bring[j & 3][ufin];
                float d0=0,d1=0,d2=0,d3=0,d4=0,d5=0,d6=0,d7=0;
#pragma unroll
                for (int c = 0; c < 16; c += 4) {
                    float4 hv = *(const float4*)&hp[c];
                    d0 = fmaf(wA[0][c],hv.x,d0); d0 = fmaf(wA[0][c+1],hv.y,d0); d0 = fmaf(wA[0][c+2],hv.z,d0); d0 = fmaf(wA[0][c+3],hv.w,d0);
                    d1 = fmaf(wA[1][c],hv.x,d1); d1 = fmaf(wA[1][c+1],hv.y,d1); d1 = fmaf(wA[1][c+2],hv.z,d1); d1 = fmaf(wA[1][c+3],hv.w,d1);
                    d2 = fmaf(wA[2][c],hv.x,d2); d2 = fmaf(wA[2][c+1],hv.y,d2); d2 = fmaf(wA[2][c+2],hv.z,d2); d2 = fmaf(wA[2][c+3],hv.w,d2);
                    d3 = fmaf(wA[3][c],hv.x,d3); d3 = fmaf(wA[3][c+1],hv.y,d3); d3 = fmaf(wA[3][c+2],hv.z,d3); d3 = fmaf(wA[3][c+3],hv.w,d3);
                    d4 = fmaf(wA[4][c],hv.x,d4); d4 = fmaf(wA[4][c+1],hv.y,d4); d4 = fmaf(wA[4][c+2],hv.z,d4); d4 = fmaf(wA[4][c+3],hv.w,d4);
                    d5 = fmaf(wA[5][c],hv.x,d5); d5 = fmaf(wA[5][c+1],hv.y,d5); d5 = fmaf(wA[5][c+2],hv.z,d5); d5 = fmaf(wA[5][c+3],hv.w,d5);
                    d6 = fmaf(wA[6][c],hv.x,d6); d6 = fmaf(wA[6][c+1],hv.y,d6); d6 = fmaf(wA[6][c+2],hv.z,d6); d6 = fmaf(wA[6][c+3],hv.w,d6);
                    d7 = fmaf(wA[7][c],hv.x,d7); d7 = fmaf(wA[7][c+1],hv.y,d7); d7 = fmaf(wA[7][c+2],hv.z,d7); d7 = fmaf(wA[7][c+3],hv.w,d7);
                }
                float e0 = (b0 ? d4 : d0) + dppf<XOR1>(b0 ? d0 : d4);
                float e1 = (b0 ? d5 : d1) + dppf<XOR1>(b0 ? d1 : d5);
                float e2 = (b0 ? d6 : d2) + dppf<XOR1>(b0 ? d2 : d6);
                float e3 = (b0 ? d7 : d3) + dppf<XOR1>(b0 ? d3 : d7);
                float g0 = (b1 ? e2 : e0) + dppf<XOR2>(b1 ? e0 : e2);
                float g1 = (b1 ? e3 : e1) + dppf<XOR2>(b1 ? e1 : e3);
                float f  = (b2 ? g1 : g0) + dppf<XOR8>(b2 ? g0 : g1);
                float h1v = fast_tanh(Bg + f);
                h1ring[j & 3][wo] = h1v;
                sbuf[j] = h1v;
                if (j == 7) {                  // burst-write t = ko-2 .. ko+5
                    const int t0 = ko - 2;
#pragma unroll
                    for (int i = 0; i < 8; ++i)
                        orow[(size_t)(t0 + i) * H] = sbuf[i];
                }
                sync_fast();
            }
        }
        // no trailing barriers needed for S1 (last interval is 1025)
    }
}

// ---------------------------------------------------------------------------
extern "C" void kernel_launch(void* const* d_in, const int* in_sizes, int n_in,
                              void* d_out, int out_size, void* d_ws, size_t ws_size,
                              hipStream_t stream) {
    const float* x     = (const float*)d_in[0];
    const float* W_ih0 = (const float*)d_in[1];
    const float* W_hh0 = (const float*)d_in[2];
    const float* b_ih0 = (const float*)d_in[3];
    const float* b_hh0 = (const float*)d_in[4];
    const float* W_ih1 = (const float*)d_in[5];
    const float* W_hh1 = (const float*)d_in[6];
    const float* b_ih1 = (const float*)d_in[7];
    const float* b_hh1 = (const float*)d_in[8];

    float* out = (float*)d_out;

    fused_rnn<<<BATCH, 512, 0, stream>>>(x, W_ih0, W_hh0, b_ih0, b_hh0,
                                         W_ih1, W_hh1, b_ih1, b_hh1, out);
}